// Round 2
// baseline (964.927 us; speedup 1.0000x reference)
//
#include <hip/hip_runtime.h>
#include <hip/hip_bf16.h>

#define BDIM 4
#define VDIM 20000
#define DDIM 64
#define RDIM 64
#define EDIM 200000
#define BV (BDIM*VDIM)
#define LN_EPS 1e-5f
#define NBB 250           // qkproj blocks per batch
#define GMD 1000          // dense-kernel grid (16 rows/block-iter, 5 iters)

typedef __hip_bfloat16 bf16;

__device__ __forceinline__ float ldf(const float* p, size_t i){ return p[i]; }
__device__ __forceinline__ float ldf(const bf16* p, size_t i){ return __bfloat162float(p[i]); }
__device__ __forceinline__ void stf(float* p, size_t i, float v){ p[i] = v; }
__device__ __forceinline__ void stf(bf16* p, size_t i, float v){ p[i] = __float2bfloat16(v); }

__device__ __forceinline__ float dot4(float4 a, float4 b){
  return a.x*b.x + a.y*b.y + a.z*b.z + a.w*b.w;
}

// Wave-private LDS ordering: DS ops from one wave execute in order, so
// write->read of wave-private LDS needs no s_barrier; just fence compiler.
__device__ __forceinline__ void wsync(){
  __builtin_amdgcn_wave_barrier();
  __asm__ volatile("" ::: "memory");
}

// ---- diagnostic fill ----
__global__ void fill_kernel(float* __restrict__ out, float v, int n){
  int t = blockIdx.x * 256 + threadIdx.x;
  if (t < n) out[t] = v;
}

// ---- detect 64-bit index layout once ----
__global__ void detect_kernel(const int* __restrict__ ei_raw, int* __restrict__ flag){
  int tid = threadIdx.x;
  int nz = 0;
  for (int j = 2*tid + 1; j < 1024; j += 512) nz |= (ei_raw[j] != 0);
  nz = __any(nz);
  __shared__ int r[4];
  if ((tid & 63) == 0) r[tid >> 6] = nz;
  __syncthreads();
  if (tid == 0) flag[0] = (r[0] | r[1] | r[2] | r[3]) ? 0 : 1;   // 1 => 64-bit
}

__global__ void prep_idx_kernel(const int* __restrict__ ei_raw, const int* __restrict__ hi_raw,
                                const int* __restrict__ flag,
                                int* __restrict__ ei, int* __restrict__ hi){
  int is64 = flag[0];
  int t = blockIdx.x * 256 + threadIdx.x;
  if (t < 3*EDIM) ei[t] = is64 ? ei_raw[2*t] : ei_raw[t];
  if (t < BDIM)   hi[t] = is64 ? hi_raw[2*t] : hi_raw[t];
}

__global__ void zero_kernel(int* __restrict__ counts){
  int i = blockIdx.x * 256 + threadIdx.x;
  if (i < VDIM + 1) counts[i] = 0;
}

__global__ void count_kernel(const int* __restrict__ ei, int* __restrict__ counts){
  int e = blockIdx.x * 256 + threadIdx.x;
  if (e < EDIM){
    int dst = ei[e*3], rel = ei[e*3+1], src = ei[e*3+2];
    if ((unsigned)dst < VDIM && (unsigned)rel < RDIM && (unsigned)src < VDIM)
      atomicAdd(&counts[dst], 1);
  }
}

// ---- scan: per-thread segments + one wave scan, 1 barrier total ----
__global__ void scan_kernel(const int* __restrict__ counts, int* __restrict__ row_ptr, int* __restrict__ cursor){
  __shared__ int wsum[4];
  int tid = threadIdx.x, lane = tid & 63, wid = tid >> 6;
  const int SEG = (VDIM + 255) / 256;        // 79
  int lo = tid * SEG;
  int hi = lo + SEG; if (hi > VDIM) hi = VDIM;
  int s = 0;
  for (int i = lo; i < hi; i++) s += counts[i];
  int x = s;
  #pragma unroll
  for (int o = 1; o < 64; o <<= 1){
    int t = __shfl_up(x, o, 64);
    if (lane >= o) x += t;
  }
  if (lane == 63) wsum[wid] = x;
  __syncthreads();
  int wo = 0;
  for (int w = 0; w < wid; w++) wo += wsum[w];
  int run = wo + x - s;                      // exclusive prefix of this thread's segment
  for (int i = lo; i < hi; i++){
    row_ptr[i] = run; cursor[i] = run; run += counts[i];
  }
  if (tid == 255) row_ptr[VDIM] = run;       // total
}

__global__ void scatter_kernel(const int* __restrict__ ei, int* __restrict__ cursor,
                               int2* __restrict__ pk){
  int e = blockIdx.x * 256 + threadIdx.x;
  if (e < EDIM){
    int dst = ei[e*3], rel = ei[e*3+1], src = ei[e*3+2];
    if ((unsigned)dst < VDIM && (unsigned)rel < RDIM && (unsigned)src < VDIM){
      int p = atomicAdd(&cursor[dst], 1);
      pk[p] = make_int2(rel, src);
    }
  }
}

// ---- z projections (float4 weight reads) ----
__global__ void zcalc_kernel(const float* __restrict__ z,
                             const float* __restrict__ qkzw, const float* __restrict__ qkzb,
                             const float* __restrict__ vfw,  const float* __restrict__ vfb,
                             float* __restrict__ qk_z, float* __restrict__ zr){
  int idx = blockIdx.x * 256 + threadIdx.x;
  if (idx >= 49152) return;
  int which = idx >> 14;
  int r = idx & 16383;
  int b = r >> 12;
  int j = r & 4095;
  const float* wrow; float bias; float* outp;
  if (which == 0){ wrow = qkzw + (size_t)j*DDIM; bias = qkzb[j]; outp = qk_z; }
  else { int i = which - 1; wrow = vfw + (size_t)(i*4096 + j)*DDIM; bias = vfb[i*4096 + j]; outp = zr + i*16384; }
  const float4* zr4 = (const float4*)(z + (size_t)b*DDIM);
  const float4* wr4 = (const float4*)wrow;
  float acc = bias;
  #pragma unroll
  for (int i = 0; i < 16; i++) acc += dot4(zr4[i], wr4[i]);
  outp[r] = acc;
}

// ---- rspmm gather (CSR, packed idx), 2 edges in flight ----
template<typename T>
__global__ __launch_bounds__(256) void rspmm_gather(
    const int* __restrict__ row_ptr, const int2* __restrict__ pk,
    const float* __restrict__ zrel, const T* __restrict__ X, T* __restrict__ out){
  int v = blockIdx.x;
  int b = threadIdx.x >> 6, d = threadIdx.x & 63;
  int s = row_ptr[v], e = row_ptr[v+1];
  const float* zb = zrel + b*RDIM*DDIM + d;
  size_t xb = (size_t)b*VDIM*64 + d;
  float acc0 = 0.f, acc1 = 0.f;
  int i = s;
  for (; i + 2 <= e; i += 2){
    int2 e0 = pk[i], e1 = pk[i+1];
    float x0 = ldf(X, xb + (size_t)e0.y*64);
    float x1 = ldf(X, xb + (size_t)e1.y*64);
    acc0 += zb[(size_t)e0.x*64] * x0;
    acc1 += zb[(size_t)e1.x*64] * x1;
  }
  if (i < e){
    int2 ed = pk[i];
    acc0 += zb[(size_t)ed.x*64] * ldf(X, xb + (size_t)ed.y*64);
  }
  stf(out, ((size_t)b*VDIM + v)*64 + d, acc0 + acc1);
}

// ---- init qk_x: 4 rows/wave, weights in regs ----
template<typename T>
__global__ __launch_bounds__(256, 1) void init_qk_kernel(
    const float* __restrict__ x, const float* __restrict__ noise,
    const float* __restrict__ w1, const float* __restrict__ b1,
    const float* __restrict__ w2, const float* __restrict__ b2,
    T* __restrict__ out){
  __shared__ __align__(16) float tb[16*64];
  __shared__ __align__(16) float hb[16*64];
  int tid = threadIdx.x, lane = tid & 63, wid = tid >> 6;
  float w1a[64]; float4 w2r[16];
  #pragma unroll
  for (int i = 0; i < 64; i++) w1a[i] = w1[lane*65 + i];
  float wn = w1[lane*65 + 64];
  const float4* w2v = (const float4*)w2;
  #pragma unroll
  for (int i = 0; i < 16; i++) w2r[i] = w2v[lane*16 + i];
  float b1l = b1[lane], b2l = b2[lane];
  const float4* tbv = (const float4*)tb;
  const float4* hbv = (const float4*)hb;
  int tbase = wid*256 + lane;
  int fbase = wid*64;
  for (int r0 = blockIdx.x*16; r0 < BV; r0 += gridDim.x*16){
    int row0 = r0 + wid*4;
    size_t rb = (size_t)row0*64 + lane;
    float x0 = x[rb], x1 = x[rb+64], x2 = x[rb+128], x3 = x[rb+192];
    float n0 = noise[row0], n1 = noise[row0+1], n2 = noise[row0+2], n3 = noise[row0+3];
    tb[tbase] = x0; tb[tbase+64] = x1; tb[tbase+128] = x2; tb[tbase+192] = x3;
    wsync();
    float h0 = b1l + wn*n0, h1 = b1l + wn*n1, h2 = b1l + wn*n2, h3 = b1l + wn*n3;
    #pragma unroll
    for (int i4 = 0; i4 < 16; i4++){
      float4 t0 = tbv[fbase + i4],      t1 = tbv[fbase + 16 + i4];
      float4 t2 = tbv[fbase + 32 + i4], t3 = tbv[fbase + 48 + i4];
      float wa = w1a[i4*4+0], wb = w1a[i4*4+1], wc = w1a[i4*4+2], wd = w1a[i4*4+3];
      h0 += wa*t0.x + wb*t0.y + wc*t0.z + wd*t0.w;
      h1 += wa*t1.x + wb*t1.y + wc*t1.z + wd*t1.w;
      h2 += wa*t2.x + wb*t2.y + wc*t2.z + wd*t2.w;
      h3 += wa*t3.x + wb*t3.y + wc*t3.z + wd*t3.w;
    }
    hb[tbase]     = fmaxf(h0, 0.f);
    hb[tbase+64]  = fmaxf(h1, 0.f);
    hb[tbase+128] = fmaxf(h2, 0.f);
    hb[tbase+192] = fmaxf(h3, 0.f);
    wsync();
    float y0 = b2l, y1 = b2l, y2 = b2l, y3 = b2l;
    #pragma unroll
    for (int i4 = 0; i4 < 16; i4++){
      float4 w = w2r[i4];
      y0 += dot4(w, hbv[fbase + i4]);
      y1 += dot4(w, hbv[fbase + 16 + i4]);
      y2 += dot4(w, hbv[fbase + 32 + i4]);
      y3 += dot4(w, hbv[fbase + 48 + i4]);
    }
    stf(out, rb, y0); stf(out, rb+64, y1); stf(out, rb+128, y2); stf(out, rb+192, y3);
    wsync();
  }
}

// ---- init v_x: 4 rows/wave ----
template<typename T>
__global__ __launch_bounds__(256, 1) void init_v_kernel(
    const float* __restrict__ x, const int* __restrict__ h_index,
    const float* __restrict__ w1, const float* __restrict__ b1,
    const float* __restrict__ w2, const float* __restrict__ b2,
    T* __restrict__ out){
  __shared__ __align__(16) float tb[16*64];
  __shared__ __align__(16) float hb[16*64];
  int tid = threadIdx.x, lane = tid & 63, wid = tid >> 6;
  float4 w1r[16], w2r[16];
  const float4* w1v = (const float4*)w1;     // [64][128] -> row stride 32 float4
  const float4* w2v = (const float4*)w2;
  #pragma unroll
  for (int i = 0; i < 16; i++){ w1r[i] = w1v[lane*32 + i]; w2r[i] = w2v[lane*16 + i]; }
  float rsv = 0.f;
  #pragma unroll
  for (int i = 0; i < 16; i++){ float4 t = w1v[lane*32 + 16 + i]; rsv += t.x+t.y+t.z+t.w; }
  float b1l = b1[lane], b2l = b2[lane];
  int h0i = h_index[0], h1i = h_index[1], h2i = h_index[2], h3i = h_index[3];
  const float4* tbv = (const float4*)tb;
  const float4* hbv = (const float4*)hb;
  int tbase = wid*256 + lane;
  int fbase = wid*64;
  for (int r0 = blockIdx.x*16; r0 < BV; r0 += gridDim.x*16){
    int row0 = r0 + wid*4;
    int b = row0 / VDIM;                     // uniform within wave (16 | 20000)
    int vbase = row0 - b*VDIM;
    int hv = (b == 0) ? h0i : (b == 1) ? h1i : (b == 2) ? h2i : h3i;
    size_t rb = (size_t)row0*64 + lane;
    float x0 = x[rb], x1 = x[rb+64], x2 = x[rb+128], x3 = x[rb+192];
    tb[tbase] = x0; tb[tbase+64] = x1; tb[tbase+128] = x2; tb[tbase+192] = x3;
    wsync();
    float h0 = b1l + ((vbase   == hv) ? rsv : 0.f);
    float h1 = b1l + ((vbase+1 == hv) ? rsv : 0.f);
    float h2 = b1l + ((vbase+2 == hv) ? rsv : 0.f);
    float h3 = b1l + ((vbase+3 == hv) ? rsv : 0.f);
    #pragma unroll
    for (int i4 = 0; i4 < 16; i4++){
      float4 w = w1r[i4];
      h0 += dot4(w, tbv[fbase + i4]);
      h1 += dot4(w, tbv[fbase + 16 + i4]);
      h2 += dot4(w, tbv[fbase + 32 + i4]);
      h3 += dot4(w, tbv[fbase + 48 + i4]);
    }
    hb[tbase]     = fmaxf(h0, 0.f);
    hb[tbase+64]  = fmaxf(h1, 0.f);
    hb[tbase+128] = fmaxf(h2, 0.f);
    hb[tbase+192] = fmaxf(h3, 0.f);
    wsync();
    float y0 = b2l, y1 = b2l, y2 = b2l, y3 = b2l;
    #pragma unroll
    for (int i4 = 0; i4 < 16; i4++){
      float4 w = w2r[i4];
      y0 += dot4(w, hbv[fbase + i4]);
      y1 += dot4(w, hbv[fbase + 16 + i4]);
      y2 += dot4(w, hbv[fbase + 32 + i4]);
      y3 += dot4(w, hbv[fbase + 48 + i4]);
    }
    stf(out, rb, y0); stf(out, rb+64, y1); stf(out, rb+128, y2); stf(out, rb+192, y3);
    wsync();
  }
}

// ---- loop body: X = LN(mlp2(O + alpha*X))*ng + nb + X ; 4 rows/wave ----
template<typename T>
__global__ __launch_bounds__(256, 1) void loop_body_kernel(
    const T* __restrict__ O, T* __restrict__ X,
    const float* __restrict__ alpha, const float* __restrict__ w1, const float* __restrict__ b1,
    const float* __restrict__ w2, const float* __restrict__ b2,
    const float* __restrict__ ng, const float* __restrict__ nb){
  __shared__ __align__(16) float tb[16*64];
  __shared__ __align__(16) float hb[16*64];
  int tid = threadIdx.x, lane = tid & 63, wid = tid >> 6;
  float4 w1r[16], w2r[16];
  const float4* w1v = (const float4*)w1;
  const float4* w2v = (const float4*)w2;
  #pragma unroll
  for (int i = 0; i < 16; i++){ w1r[i] = w1v[lane*16 + i]; w2r[i] = w2v[lane*16 + i]; }
  float all = alpha[lane], b1l = b1[lane], b2l = b2[lane];
  float ngl = ng[lane], nbl = nb[lane];
  const float4* tbv = (const float4*)tb;
  const float4* hbv = (const float4*)hb;
  int tbase = wid*256 + lane;
  int fbase = wid*64;
  for (int r0 = blockIdx.x*16; r0 < BV; r0 += gridDim.x*16){
    size_t rb = ((size_t)r0 + wid*4)*64 + lane;
    float xs0 = ldf(X, rb),     ov0 = ldf(O, rb);
    float xs1 = ldf(X, rb+64),  ov1 = ldf(O, rb+64);
    float xs2 = ldf(X, rb+128), ov2 = ldf(O, rb+128);
    float xs3 = ldf(X, rb+192), ov3 = ldf(O, rb+192);
    tb[tbase]     = ov0 + all*xs0;
    tb[tbase+64]  = ov1 + all*xs1;
    tb[tbase+128] = ov2 + all*xs2;
    tb[tbase+192] = ov3 + all*xs3;
    wsync();
    float h0=b1l, h1=b1l, h2=b1l, h3=b1l;
    #pragma unroll
    for (int i4 = 0; i4 < 16; i4++){
      float4 w = w1r[i4];
      h0 += dot4(w, tbv[fbase + i4]);
      h1 += dot4(w, tbv[fbase + 16 + i4]);
      h2 += dot4(w, tbv[fbase + 32 + i4]);
      h3 += dot4(w, tbv[fbase + 48 + i4]);
    }
    hb[tbase]     = fmaxf(h0, 0.f);
    hb[tbase+64]  = fmaxf(h1, 0.f);
    hb[tbase+128] = fmaxf(h2, 0.f);
    hb[tbase+192] = fmaxf(h3, 0.f);
    wsync();
    float y0=b2l, y1=b2l, y2=b2l, y3=b2l;
    #pragma unroll
    for (int i4 = 0; i4 < 16; i4++){
      float4 w = w2r[i4];
      y0 += dot4(w, hbv[fbase + i4]);
      y1 += dot4(w, hbv[fbase + 16 + i4]);
      y2 += dot4(w, hbv[fbase + 32 + i4]);
      y3 += dot4(w, hbv[fbase + 48 + i4]);
    }
    // fused one-pass LN moments, 8 interleaved chains
    float s0=y0, s1=y1, s2=y2, s3=y3;
    float q0=y0*y0, q1=y1*y1, q2=y2*y2, q3=y3*y3;
    #pragma unroll
    for (int o = 32; o > 0; o >>= 1){
      s0 += __shfl_xor(s0,o,64); q0 += __shfl_xor(q0,o,64);
      s1 += __shfl_xor(s1,o,64); q1 += __shfl_xor(q1,o,64);
      s2 += __shfl_xor(s2,o,64); q2 += __shfl_xor(q2,o,64);
      s3 += __shfl_xor(s3,o,64); q3 += __shfl_xor(q3,o,64);
    }
    float mu, var;
    mu = s0*(1.f/64.f); var = fmaxf(q0*(1.f/64.f) - mu*mu, 0.f);
    stf(X, rb,     (y0-mu)*rsqrtf(var+LN_EPS)*ngl + nbl + xs0);
    mu = s1*(1.f/64.f); var = fmaxf(q1*(1.f/64.f) - mu*mu, 0.f);
    stf(X, rb+64,  (y1-mu)*rsqrtf(var+LN_EPS)*ngl + nbl + xs1);
    mu = s2*(1.f/64.f); var = fmaxf(q2*(1.f/64.f) - mu*mu, 0.f);
    stf(X, rb+128, (y2-mu)*rsqrtf(var+LN_EPS)*ngl + nbl + xs2);
    mu = s3*(1.f/64.f); var = fmaxf(q3*(1.f/64.f) - mu*mu, 0.f);
    stf(X, rb+192, (y3-mu)*rsqrtf(var+LN_EPS)*ngl + nbl + xs3);
    wsync();
  }
}

// ---- qkproj: 4 rows/wave, weights in regs, per-block partial reduction ----
template<typename T>
__global__ __launch_bounds__(256, 1) void qkproj_kernel(
    T* __restrict__ Xqk, const T* __restrict__ Xv,
    const float* __restrict__ w, const float* __restrict__ bias,
    float* __restrict__ partial){
  __shared__ __align__(16) float tb[16*64];
  __shared__ __align__(16) float red[4*1152];
  int tid = threadIdx.x, lane = tid & 63, wid = tid >> 6;
  float4 wq[16], wk[16];
  const float4* wv = (const float4*)w;
  #pragma unroll
  for (int i = 0; i < 16; i++){ wq[i] = wv[lane*16 + i]; wk[i] = wv[(64+lane)*16 + i]; }
  float bq = bias[lane], bk = bias[64+lane];
  int b = blockIdx.x / NBB, blk = blockIdx.x % NBB;
  float kv[16];
  #pragma unroll
  for (int i = 0; i < 16; i++) kv[i] = 0.f;
  float ks = 0.f, vs = 0.f;
  const float4* tbv = (const float4*)tb;
  int tbase = wid*256 + lane;
  int fbase = wid*64;
  int base = lane & 48;                      // h*16
  const int STEPS = VDIM / (NBB*16);         // 5
  size_t row = ((size_t)b*VDIM + blk*16 + wid*4)*64 + lane;
  const size_t rstride = (size_t)NBB*16*64;
  for (int st = 0; st < STEPS; st++){
    float x0 = ldf(Xqk, row),     x1 = ldf(Xqk, row+64);
    float x2 = ldf(Xqk, row+128), x3 = ldf(Xqk, row+192);
    float vv0 = ldf(Xv, row),     vv1 = ldf(Xv, row+64);
    float vv2 = ldf(Xv, row+128), vv3 = ldf(Xv, row+192);
    tb[tbase] = x0; tb[tbase+64] = x1; tb[tbase+128] = x2; tb[tbase+192] = x3;
    wsync();
    float q0=bq,q1=bq,q2=bq,q3=bq, k0=bk,k1=bk,k2=bk,k3=bk;
    #pragma unroll
    for (int i4 = 0; i4 < 16; i4++){
      float4 t0 = tbv[fbase + i4],      t1 = tbv[fbase + 16 + i4];
      float4 t2 = tbv[fbase + 32 + i4], t3 = tbv[fbase + 48 + i4];
      float4 a = wq[i4], c = wk[i4];
      q0 += dot4(a, t0); k0 += dot4(c, t0);
      q1 += dot4(a, t1); k1 += dot4(c, t1);
      q2 += dot4(a, t2); k2 += dot4(c, t2);
      q3 += dot4(a, t3); k3 += dot4(c, t3);
    }
    // per-head 16-lane norms, 8 interleaved chains
    float a0=q0*q0, a1=q1*q1, a2=q2*q2, a3=q3*q3;
    float c0=k0*k0, c1=k1*k1, c2=k2*k2, c3=k3*k3;
    #pragma unroll
    for (int o = 8; o > 0; o >>= 1){
      a0 += __shfl_xor(a0,o,64); c0 += __shfl_xor(c0,o,64);
      a1 += __shfl_xor(a1,o,64); c1 += __shfl_xor(c1,o,64);
      a2 += __shfl_xor(a2,o,64); c2 += __shfl_xor(c2,o,64);
      a3 += __shfl_xor(a3,o,64); c3 += __shfl_xor(c3,o,64);
    }
    q0 /= fmaxf(sqrtf(a0), 1e-12f); k0 /= fmaxf(sqrtf(c0), 1e-12f);
    q1 /= fmaxf(sqrtf(a1), 1e-12f); k1 /= fmaxf(sqrtf(c1), 1e-12f);
    q2 /= fmaxf(sqrtf(a2), 1e-12f); k2 /= fmaxf(sqrtf(c2), 1e-12f);
    q3 /= fmaxf(sqrtf(a3), 1e-12f); k3 /= fmaxf(sqrtf(c3), 1e-12f);
    stf(Xqk, row, q0); stf(Xqk, row+64, q1); stf(Xqk, row+128, q2); stf(Xqk, row+192, q3);
    ks += k0 + k1 + k2 + k3;
    vs += vv0 + vv1 + vv2 + vv3;
    #pragma unroll
    for (int dl = 0; dl < 16; dl++){
      kv[dl] += k0*__shfl(vv0, base+dl, 64)
              + k1*__shfl(vv1, base+dl, 64)
              + k2*__shfl(vv2, base+dl, 64)
              + k3*__shfl(vv3, base+dl, 64);
    }
    row += rstride;
    wsync();
  }
  // per-wave partials -> LDS -> block partial (coalesced)
  float* rw = red + wid*1152;
  #pragma unroll
  for (int dl = 0; dl < 16; dl++) rw[lane*16 + dl] = kv[dl];
  rw[1024 + lane] = ks;
  rw[1088 + lane] = vs;
  __syncthreads();
  float* P = partial + (size_t)blockIdx.x*1152;
  for (int j = tid; j < 1152; j += 256)
    P[j] = red[j] + red[1152+j] + red[2304+j] + red[3456+j];
}

// ---- reduce qkproj partials ----
__global__ void qkred_kernel(const float* __restrict__ partial,
                             float* __restrict__ kvs, float* __restrict__ ksum, float* __restrict__ vsum){
  int b = blockIdx.x / 5, ch = blockIdx.x % 5;
  int j = ch*256 + threadIdx.x;
  if (j >= 1152) return;
  const float* P = partial + (size_t)b*NBB*1152;
  float s = 0.f;
  for (int t = 0; t < NBB; t++) s += P[(size_t)t*1152 + j];
  if (j < 1024)      kvs[b*1024 + j] = s;
  else if (j < 1088) ksum[b*64 + (j-1024)] = s;
  else               vsum[b*64 + (j-1088)] = s;
}

// ---- attention finalize + LN: 4 rows/wave ----
template<typename T>
__global__ __launch_bounds__(256) void attn_final_kernel(
    const float* __restrict__ x, T* __restrict__ A, const T* __restrict__ Xv,
    const float* __restrict__ kvs, const float* __restrict__ ksum, const float* __restrict__ vsum,
    const float* __restrict__ g, const float* __restrict__ bb){
  __shared__ float kvss[4096], kss[256], vss[256];
  int tid = threadIdx.x, lane = tid & 63, wid = tid >> 6;
  for (int i = tid; i < 4096; i += 256) kvss[i] = kvs[i];
  kss[tid] = ksum[tid];
  vss[tid] = vsum[tid];
  float gl = g[lane], bl = bb[lane];
  __syncthreads();
  int h16 = lane & 48, dl = lane & 15;
  for (int r0 = blockIdx.x*16; r0 < BV; r0 += gridDim.x*16){
    int row0 = r0 + wid*4;
    int b = row0 / VDIM;                     // uniform within wave
    size_t rb = (size_t)row0*64 + lane;
    float qv0 = ldf(A, rb),     qv1 = ldf(A, rb+64);
    float qv2 = ldf(A, rb+128), qv3 = ldf(A, rb+192);
    float vv0 = ldf(Xv, rb),     vv1 = ldf(Xv, rb+64);
    float vv2 = ldf(Xv, rb+128), vv3 = ldf(Xv, rb+192);
    float xv0 = x[rb], xv1 = x[rb+64], xv2 = x[rb+128], xv3 = x[rb+192];
    float vsb = vss[b*64+lane];
    float num0 = vsb + vv0*(float)VDIM, num1 = vsb + vv1*(float)VDIM;
    float num2 = vsb + vv2*(float)VDIM, num3 = vsb + vv3*(float)VDIM;
    float den0 = 2.0f*(float)VDIM, den1 = den0, den2 = den0, den3 = den0;
    int kbase = b*1024 + h16*16 + dl;
    int ksbase = b*64 + h16;
    #pragma unroll
    for (int j = 0; j < 16; j++){
      float kvj = kvss[kbase + j*16];
      float ksj = kss[ksbase + j];
      float qj0 = __shfl(qv0, h16 + j, 64);
      float qj1 = __shfl(qv1, h16 + j, 64);
      float qj2 = __shfl(qv2, h16 + j, 64);
      float qj3 = __shfl(qv3, h16 + j, 64);
      num0 += qj0*kvj; den0 += qj0*ksj;
      num1 += qj1*kvj; den1 += qj1*ksj;
      num2 += qj2*kvj; den2 += qj2*ksj;
      num3 += qj3*kvj; den3 += qj3*ksj;
    }
    float y0 = xv0 + num0/den0, y1 = xv1 + num1/den1;
    float y2 = xv2 + num2/den2, y3 = xv3 + num3/den3;
    float s0=y0, s1=y1, s2=y2, s3=y3;
    float q0=y0*y0, q1=y1*y1, q2=y2*y2, q3=y3*y3;
    #pragma unroll
    for (int o = 32; o > 0; o >>= 1){
      s0 += __shfl_xor(s0,o,64); q0 += __shfl_xor(q0,o,64);
      s1 += __shfl_xor(s1,o,64); q1 += __shfl_xor(q1,o,64);
      s2 += __shfl_xor(s2,o,64); q2 += __shfl_xor(q2,o,64);
      s3 += __shfl_xor(s3,o,64); q3 += __shfl_xor(q3,o,64);
    }
    float mu, var;
    mu = s0*(1.f/64.f); var = fmaxf(q0*(1.f/64.f) - mu*mu, 0.f);
    stf(A, rb,     (y0-mu)*rsqrtf(var+LN_EPS)*gl + bl);
    mu = s1*(1.f/64.f); var = fmaxf(q1*(1.f/64.f) - mu*mu, 0.f);
    stf(A, rb+64,  (y1-mu)*rsqrtf(var+LN_EPS)*gl + bl);
    mu = s2*(1.f/64.f); var = fmaxf(q2*(1.f/64.f) - mu*mu, 0.f);
    stf(A, rb+128, (y2-mu)*rsqrtf(var+LN_EPS)*gl + bl);
    mu = s3*(1.f/64.f); var = fmaxf(q3*(1.f/64.f) - mu*mu, 0.f);
    stf(A, rb+192, (y3-mu)*rsqrtf(var+LN_EPS)*gl + bl);
  }
}

// ---- final FFN + LN -> fp32 out: 4 rows/wave ----
template<typename T>
__global__ __launch_bounds__(256, 1) void final_kernel(
    const T* __restrict__ X1,
    const float* __restrict__ w1, const float* __restrict__ b1,
    const float* __restrict__ w2, const float* __restrict__ b2,
    const float* __restrict__ g, const float* __restrict__ bb,
    float* __restrict__ out){
  __shared__ __align__(16) float tb[16*64];
  __shared__ __align__(16) float hb[16*64];
  int tid = threadIdx.x, lane = tid & 63, wid = tid >> 6;
  float4 w1r[16], w2r[16];
  const float4* w1v = (const float4*)w1;
  const float4* w2v = (const float4*)w2;
  #pragma unroll
  for (int i = 0; i < 16; i++){ w1r[i] = w1v[lane*16 + i]; w2r[i] = w2v[lane*16 + i]; }
  float b1l = b1[lane], b2l = b2[lane], gl = g[lane], bl = bb[lane];
  const float4* tbv = (const float4*)tb;
  const float4* hbv = (const float4*)hb;
  int tbase = wid*256 + lane;
  int fbase = wid*64;
  for (int r0 = blockIdx.x*16; r0 < BV; r0 += gridDim.x*16){
    size_t rb = ((size_t)r0 + wid*4)*64 + lane;
    float x0 = ldf(X1, rb),     x1 = ldf(X1, rb+64);
    float x2 = ldf(X1, rb+128), x3 = ldf(X1, rb+192);
    tb[tbase] = x0; tb[tbase+64] = x1; tb[tbase+128] = x2; tb[tbase+192] = x3;
    wsync();
    float h0=b1l, h1=b1l, h2=b1l, h3=b1l;
    #pragma unroll
    for (int i4 = 0; i4 < 16; i4++){
      float4 w = w1r[i4];
      h0 += dot4(w, tbv[fbase + i4]);
      h1 += dot4(w, tbv[fbase + 16 + i4]);
      h2 += dot4(w, tbv[fbase + 32 + i4]);
      h3 += dot4(w, tbv[fbase + 48 + i4]);
    }
    hb[tbase]     = fmaxf(h0, 0.f);
    hb[tbase+64]  = fmaxf(h1, 0.f);
    hb[tbase+128] = fmaxf(h2, 0.f);
    hb[tbase+192] = fmaxf(h3, 0.f);
    wsync();
    float y0=b2l, y1=b2l, y2=b2l, y3=b2l;
    #pragma unroll
    for (int i4 = 0; i4 < 16; i4++){
      float4 w = w2r[i4];
      y0 += dot4(w, hbv[fbase + i4]);
      y1 += dot4(w, hbv[fbase + 16 + i4]);
      y2 += dot4(w, hbv[fbase + 32 + i4]);
      y3 += dot4(w, hbv[fbase + 48 + i4]);
    }
    float t0 = x0 + y0, t1 = x1 + y1, t2 = x2 + y2, t3 = x3 + y3;
    float s0=t0, s1=t1, s2=t2, s3=t3;
    float q0=t0*t0, q1=t1*t1, q2=t2*t2, q3=t3*t3;
    #pragma unroll
    for (int o = 32; o > 0; o >>= 1){
      s0 += __shfl_xor(s0,o,64); q0 += __shfl_xor(q0,o,64);
      s1 += __shfl_xor(s1,o,64); q1 += __shfl_xor(q1,o,64);
      s2 += __shfl_xor(s2,o,64); q2 += __shfl_xor(q2,o,64);
      s3 += __shfl_xor(s3,o,64); q3 += __shfl_xor(q3,o,64);
    }
    float mu, var;
    mu = s0*(1.f/64.f); var = fmaxf(q0*(1.f/64.f) - mu*mu, 0.f);
    out[rb]     = (t0-mu)*rsqrtf(var+LN_EPS)*gl + bl;
    mu = s1*(1.f/64.f); var = fmaxf(q1*(1.f/64.f) - mu*mu, 0.f);
    out[rb+64]  = (t1-mu)*rsqrtf(var+LN_EPS)*gl + bl;
    mu = s2*(1.f/64.f); var = fmaxf(q2*(1.f/64.f) - mu*mu, 0.f);
    out[rb+128] = (t2-mu)*rsqrtf(var+LN_EPS)*gl + bl;
    mu = s3*(1.f/64.f); var = fmaxf(q3*(1.f/64.f) - mu*mu, 0.f);
    out[rb+192] = (t3-mu)*rsqrtf(var+LN_EPS)*gl + bl;
    wsync();
  }
}

// ================= host side =================
static const int DICT_SIZES[42] = {
  5120000,256,256,80000,262144,4096,4160,64,4096,64,
  8192,64,4096,64,8192,128,8192,128,8192,128,
  128,128,128,524288,8192,8192,128,8192,128,128,
  128,128,4096,64,4096,64,64,64,64,64,
  4,600000};

template<typename T>
static void run_pipeline(const float* const* N, const int* hi,
                         const int* row_ptr, const int2* pk,
                         float* qk_z, float* zr, float* kvs, float* part,
                         T* Obuf, T* A, T* B, float* outp, hipStream_t stream){
  float* ksum = kvs + 4096;
  float* vsum = kvs + 4352;

  zcalc_kernel<<<192, 256, 0, stream>>>(N[1], N[4], N[5], N[23], N[24], qk_z, zr);

  init_qk_kernel<T><<<GMD, 256, 0, stream>>>(N[0], N[3], N[6], N[7], N[8], N[9], A);
  for (int i = 0; i < 2; i++){
    rspmm_gather<T><<<VDIM, 256, 0, stream>>>(row_ptr, pk, qk_z, A, Obuf);
    loop_body_kernel<T><<<GMD, 256, 0, stream>>>(Obuf, A, N[20] + i*64, N[16] + i*4096, N[17] + i*64,
                                                 N[18] + i*4096, N[19] + i*64, N[21] + i*64, N[22] + i*64);
  }
  init_v_kernel<T><<<GMD, 256, 0, stream>>>(N[0], hi, N[10], N[11], N[12], N[13], B);
  for (int i = 0; i < 2; i++){
    rspmm_gather<T><<<VDIM, 256, 0, stream>>>(row_ptr, pk, zr + i*16384, B, Obuf);
    loop_body_kernel<T><<<GMD, 256, 0, stream>>>(Obuf, B, N[29] + i*64, N[25] + i*4096, N[26] + i*64,
                                                 N[27] + i*4096, N[28] + i*64, N[30] + i*64, N[31] + i*64);
  }
  qkproj_kernel<T><<<BDIM*NBB, 256, 0, stream>>>(A, B, N[14], N[15], part);
  qkred_kernel<<<20, 256, 0, stream>>>(part, kvs, ksum, vsum);
  attn_final_kernel<T><<<GMD, 256, 0, stream>>>(N[0], A, B, kvs, ksum, vsum, N[36], N[37]);
  final_kernel<T><<<GMD, 256, 0, stream>>>(A, N[32], N[33], N[34], N[35], N[38], N[39], outp);
}

extern "C" void kernel_launch(void* const* d_in, const int* in_sizes, int n_in,
                              void* d_out, int out_size, void* d_ws, size_t ws_size,
                              hipStream_t stream){
  float* outp = (float*)d_out;
  const int GOUT = (out_size + 255) / 256;

  if (n_in != 42){
    fill_kernel<<<GOUT, 256, 0, stream>>>(outp, 2000.0f + (float)n_in, out_size);
    return;
  }
  auto sz_ok = [&](int s, int e)->bool{
    if (s == e) return true;
    if ((e == 4 || e == 600000) && s == 2*e) return true;
    return false;
  };
  int bad = -1;
  for (int i = 0; i < 42 && bad < 0; i++)
    if (!sz_ok(in_sizes[i], DICT_SIZES[i])) bad = i;
  if (bad >= 0){
    fill_kernel<<<GOUT, 256, 0, stream>>>(outp, 1000.0f + (float)bad, out_size);
    return;
  }

  const float* N[40];
  for (int i = 0; i < 40; i++) N[i] = (const float*)d_in[i];
  const int* hi_raw = (const int*)d_in[40];
  const int* ei_raw = (const int*)d_in[41];

  char* p = (char*)d_ws;
  auto alloc = [&](size_t bytes)->char*{ char* r = p; p += (bytes + 255) / 256 * 256; return r; };
  int* ei      = (int*)alloc((size_t)3*EDIM*4);
  int* hi      = (int*)alloc(256);
  int* eflag   = (int*)alloc(256);
  int* counts  = (int*)alloc((VDIM+1)*4);
  int* row_ptr = (int*)alloc((VDIM+1)*4);
  int* cursor  = (int*)alloc((VDIM+1)*4);
  int2* pk     = (int2*)alloc((size_t)EDIM*8);
  float* qk_z  = (float*)alloc(16384u*4);
  float* zr    = (float*)alloc(32768u*4);
  float* kvs   = (float*)alloc(4608u*4);
  float* part  = (float*)alloc((size_t)BDIM*NBB*1152*4);
  size_t fixed = (size_t)(p - (char*)d_ws);
  bool f32ok = ws_size >= fixed + 3*(size_t)BV*64*4 + 1024;

  detect_kernel<<<1, 256, 0, stream>>>(ei_raw, eflag);
  prep_idx_kernel<<<(3*EDIM+255)/256, 256, 0, stream>>>(ei_raw, hi_raw, eflag, ei, hi);
  zero_kernel<<<(VDIM+256)/256, 256, 0, stream>>>(counts);
  count_kernel<<<(EDIM+255)/256, 256, 0, stream>>>(ei, counts);
  scan_kernel<<<1, 256, 0, stream>>>(counts, row_ptr, cursor);
  scatter_kernel<<<(EDIM+255)/256, 256, 0, stream>>>(ei, cursor, pk);

  if (f32ok){
    float* Obuf = (float*)alloc((size_t)BV*64*4);
    float* A    = (float*)alloc((size_t)BV*64*4);
    float* B    = (float*)alloc((size_t)BV*64*4);
    run_pipeline<float>(N, hi, row_ptr, pk, qk_z, zr, kvs, part, Obuf, A, B, outp, stream);
  } else {
    bf16* Obuf = (bf16*)alloc((size_t)BV*64*2);
    bf16* A    = (bf16*)alloc((size_t)BV*64*2);
    bf16* B    = (bf16*)alloc((size_t)BV*64*2);
    run_pipeline<bf16>(N, hi, row_ptr, pk, qk_z, zr, kvs, part, Obuf, A, B, outp, stream);
  }
}